// Round 1
// baseline (762.093 us; speedup 1.0000x reference)
//
#include <hip/hip_runtime.h>
#include <hip/hip_bf16.h>
#include <cstdint>
#include <cstddef>

#define NEXP  8
#define NTOK  4096
#define HID   1024
#define INTER 3584
#define CAP   2048   // per-expert cap == reference jnp.nonzero(size=seq_len)

#define BM  128
#define BN  128
#define BK  32
#define BKP 40       // padded K stride (ushorts): rows 16B aligned, 2-way-free banks

typedef __attribute__((ext_vector_type(4))) float floatx4;
typedef __attribute__((ext_vector_type(8))) short shortx8;

__device__ __forceinline__ unsigned short f2bf(float f) {
    union { float f; unsigned u; } v; v.f = f;
    unsigned r = v.u + 0x7fffu + ((v.u >> 16) & 1u);   // RNE
    return (unsigned short)(r >> 16);
}

__device__ __forceinline__ shortx8 pack8(const float* v) {
    shortx8 r;
#pragma unroll
    for (int i = 0; i < 8; ++i) r[i] = (short)f2bf(v[i]);
    return r;
}

// ---------------- routing: per-expert token lists ----------------
__global__ void route_kernel(const int* __restrict__ mask, const float* __restrict__ rw,
                             int* __restrict__ cnt, int* __restrict__ list,
                             float* __restrict__ wgt) {
    int t = blockIdx.x * blockDim.x + threadIdx.x;
    if (t >= NTOK) return;
#pragma unroll
    for (int e = 0; e < NEXP; ++e) {
#pragma unroll
        for (int k = 0; k < 2; ++k) {
            if (mask[(e * 2 + k) * NTOK + t] != 0) {
                int pos = atomicAdd(&cnt[e], 1);
                if (pos < CAP) {
                    list[e * CAP + pos] = t;
                    wgt[e * CAP + pos] = rw[t * 2 + k];
                }
            }
        }
    }
}

// ---------------- GEMM1: H = silu(X w1) * (X w3) * rw, bf16 out ----------------
__global__ __launch_bounds__(256, 2)
void gemm1_kernel(const float* __restrict__ X, const float* __restrict__ W1,
                  const float* __restrict__ W3, const int* __restrict__ cnt,
                  const int* __restrict__ list, const float* __restrict__ wgt,
                  unsigned short* __restrict__ H) {
    const int e  = blockIdx.z;
    const int ce = min(cnt[e], CAP);
    const int m0 = blockIdx.y * BM;
    if (m0 >= ce) return;
    const int n0 = blockIdx.x * BN;

    __shared__ unsigned short lds_a [BM * BKP];
    __shared__ unsigned short lds_w1[BN * BKP];
    __shared__ unsigned short lds_w3[BN * BKP];

    const int tid = threadIdx.x;
    // A staging: thread -> (row m, half of 32-k slice)
    const int am = tid >> 1;
    const int ah = tid & 1;
    const int tok = list[e * CAP + min(m0 + am, ce - 1)];
    const float* xp = X + (size_t)tok * HID;
    // W staging: thread -> n within tile, k-group
    const int wn = tid & 127;
    const int wk = tid >> 7;   // 0/1
    const float* w1base = W1 + (size_t)e * HID * INTER + n0 + wn;
    const float* w3base = W3 + (size_t)e * HID * INTER + n0 + wn;

    const int lane = tid & 63;
    const int wave = tid >> 6;
    const int wm  = (wave >> 1) * 64;
    const int wnn = (wave & 1) * 64;
    const int fl  = lane & 15;
    const int fq  = lane >> 4;

    floatx4 acc1[4][4], acc3[4][4];
#pragma unroll
    for (int i = 0; i < 4; ++i)
#pragma unroll
        for (int j = 0; j < 4; ++j)
#pragma unroll
            for (int r = 0; r < 4; ++r) { acc1[i][j][r] = 0.f; acc3[i][j][r] = 0.f; }

    for (int k0 = 0; k0 < HID; k0 += BK) {
        __syncthreads();
        { // stage A: 16 fp32 -> 16 bf16, two b128 writes
            const float* s = xp + k0 + ah * 16;
            float v[16];
#pragma unroll
            for (int i = 0; i < 4; ++i) {
                float4 f = ((const float4*)s)[i];
                v[4*i+0]=f.x; v[4*i+1]=f.y; v[4*i+2]=f.z; v[4*i+3]=f.w;
            }
            shortx8* dst = (shortx8*)&lds_a[am * BKP + ah * 16];
            dst[0] = pack8(v);
            dst[1] = pack8(v + 8);
        }
#pragma unroll
        for (int p = 0; p < 2; ++p) { // stage W1/W3 transposed: per-lane k-gather
            const int kk = p * 16 + wk * 8;
            {
                const float* s = w1base + (size_t)(k0 + kk) * INTER;
                float v[8];
#pragma unroll
                for (int i = 0; i < 8; ++i) v[i] = s[(size_t)i * INTER];
                *(shortx8*)&lds_w1[wn * BKP + kk] = pack8(v);
            }
            {
                const float* s = w3base + (size_t)(k0 + kk) * INTER;
                float v[8];
#pragma unroll
                for (int i = 0; i < 8; ++i) v[i] = s[(size_t)i * INTER];
                *(shortx8*)&lds_w3[wn * BKP + kk] = pack8(v);
            }
        }
        __syncthreads();

        shortx8 af[4], b1[4], b3[4];
#pragma unroll
        for (int i = 0; i < 4; ++i)
            af[i] = *(const shortx8*)&lds_a[(wm + i * 16 + fl) * BKP + fq * 8];
#pragma unroll
        for (int j = 0; j < 4; ++j) {
            b1[j] = *(const shortx8*)&lds_w1[(wnn + j * 16 + fl) * BKP + fq * 8];
            b3[j] = *(const shortx8*)&lds_w3[(wnn + j * 16 + fl) * BKP + fq * 8];
        }
#pragma unroll
        for (int i = 0; i < 4; ++i)
#pragma unroll
            for (int j = 0; j < 4; ++j) {
                acc1[i][j] = __builtin_amdgcn_mfma_f32_16x16x32_bf16(af[i], b1[j], acc1[i][j], 0, 0, 0);
                acc3[i][j] = __builtin_amdgcn_mfma_f32_16x16x32_bf16(af[i], b3[j], acc3[i][j], 0, 0, 0);
            }
    }

    // epilogue: silu(a1)*a3 * rw -> bf16 H
#pragma unroll
    for (int i = 0; i < 4; ++i) {
        const int rowb = m0 + wm + i * 16 + fq * 4;
#pragma unroll
        for (int r = 0; r < 4; ++r) {
            const int row = rowb + r;
            const bool valid = row < ce;
            const float rwv = valid ? wgt[e * CAP + row] : 0.f;
            unsigned short* hp = H + (size_t)(e * CAP + (valid ? row : 0)) * INTER;
#pragma unroll
            for (int j = 0; j < 4; ++j) {
                const int col = n0 + wnn + j * 16 + fl;
                float h1 = acc1[i][j][r];
                float h3 = acc3[i][j][r];
                float sv = h1 / (1.f + __expf(-h1)) * h3 * rwv;
                if (valid) hp[col] = f2bf(sv);
            }
        }
    }
}

// ---------------- GEMM2: out[tok] += H w2 ----------------
__global__ __launch_bounds__(256, 2)
void gemm2_kernel(const unsigned short* __restrict__ H, const float* __restrict__ W2,
                  const int* __restrict__ cnt, const int* __restrict__ list,
                  float* __restrict__ out) {
    const int e  = blockIdx.z;
    const int ce = min(cnt[e], CAP);
    const int m0 = blockIdx.y * BM;
    if (m0 >= ce) return;
    const int n0 = blockIdx.x * BN;

    __shared__ unsigned short lds_a[BM * BKP];
    __shared__ unsigned short lds_w[BN * BKP];

    const int tid = threadIdx.x;
    const int am = tid >> 1;
    const int ah = tid & 1;
    const int arow = min(m0 + am, ce - 1);
    const unsigned short* hp = H + (size_t)(e * CAP + arow) * INTER;

    const int wn = tid & 127;
    const int wk = tid >> 7;
    const float* w2base = W2 + (size_t)e * INTER * HID + n0 + wn;

    const int lane = tid & 63;
    const int wave = tid >> 6;
    const int wm  = (wave >> 1) * 64;
    const int wnn = (wave & 1) * 64;
    const int fl  = lane & 15;
    const int fq  = lane >> 4;

    floatx4 acc[4][4];
#pragma unroll
    for (int i = 0; i < 4; ++i)
#pragma unroll
        for (int j = 0; j < 4; ++j)
#pragma unroll
            for (int r = 0; r < 4; ++r) acc[i][j][r] = 0.f;

    for (int k0 = 0; k0 < INTER; k0 += BK) {
        __syncthreads();
        { // A already bf16: straight copy through regs
            const shortx8* s = (const shortx8*)(hp + k0 + ah * 16);
            shortx8 v0 = s[0], v1 = s[1];
            shortx8* dst = (shortx8*)&lds_a[am * BKP + ah * 16];
            dst[0] = v0; dst[1] = v1;
        }
#pragma unroll
        for (int p = 0; p < 2; ++p) {
            const int kk = p * 16 + wk * 8;
            const float* s = w2base + (size_t)(k0 + kk) * HID;
            float v[8];
#pragma unroll
            for (int i = 0; i < 8; ++i) v[i] = s[(size_t)i * HID];
            *(shortx8*)&lds_w[wn * BKP + kk] = pack8(v);
        }
        __syncthreads();

        shortx8 af[4], bf[4];
#pragma unroll
        for (int i = 0; i < 4; ++i)
            af[i] = *(const shortx8*)&lds_a[(wm + i * 16 + fl) * BKP + fq * 8];
#pragma unroll
        for (int j = 0; j < 4; ++j)
            bf[j] = *(const shortx8*)&lds_w[(wnn + j * 16 + fl) * BKP + fq * 8];
#pragma unroll
        for (int i = 0; i < 4; ++i)
#pragma unroll
            for (int j = 0; j < 4; ++j)
                acc[i][j] = __builtin_amdgcn_mfma_f32_16x16x32_bf16(af[i], bf[j], acc[i][j], 0, 0, 0);
    }

#pragma unroll
    for (int i = 0; i < 4; ++i) {
        const int rowb = m0 + wm + i * 16 + fq * 4;
#pragma unroll
        for (int r = 0; r < 4; ++r) {
            const int row = rowb + r;
            const bool valid = row < ce;
            const int tok = valid ? list[e * CAP + row] : 0;
            float* op = out + (size_t)tok * HID;
#pragma unroll
            for (int j = 0; j < 4; ++j) {
                const int col = n0 + wnn + j * 16 + fl;
                if (valid) atomicAdd(&op[col], acc[i][j][r]);
            }
        }
    }
}

extern "C" void kernel_launch(void* const* d_in, const int* in_sizes, int n_in,
                              void* d_out, int out_size, void* d_ws, size_t ws_size,
                              hipStream_t stream) {
    const int*   mask = (const int*)  d_in[0];
    const float* X    = (const float*)d_in[1];
    const float* rw   = (const float*)d_in[2];
    const float* w1   = (const float*)d_in[3];
    const float* w2   = (const float*)d_in[4];
    const float* w3   = (const float*)d_in[5];
    float* out = (float*)d_out;

    char* ws = (char*)d_ws;
    int*   cnt  = (int*)ws;                                  // 256 B
    int*   list = (int*)(ws + 256);                          // 64 KB
    float* wgt  = (float*)(ws + 256 + 65536);                // 64 KB
    unsigned short* H = (unsigned short*)(ws + 256 + 131072); // 8*2048*3584*2 = 112 MB

    hipMemsetAsync(cnt, 0, 256, stream);
    hipMemsetAsync(d_out, 0, (size_t)out_size * sizeof(float), stream);

    route_kernel<<<dim3((NTOK + 255) / 256), dim3(256), 0, stream>>>(mask, rw, cnt, list, wgt);
    gemm1_kernel<<<dim3(INTER / BN, CAP / BM, NEXP), dim3(256), 0, stream>>>(X, w1, w3, cnt, list, wgt, H);
    gemm2_kernel<<<dim3(HID / BN, CAP / BM, NEXP), dim3(256), 0, stream>>>(H, w2, cnt, list, out);
}

// Round 2
// 722.817 us; speedup vs baseline: 1.0543x; 1.0543x over previous
//
#include <hip/hip_runtime.h>
#include <hip/hip_bf16.h>
#include <cstdint>
#include <cstddef>

#define NEXP  8
#define NTOK  4096
#define HID   1024
#define INTER 3584
#define CAP   2048   // per-expert cap == reference jnp.nonzero(size=seq_len)

#define BM  128
#define BN  128
#define BK  32

typedef __attribute__((ext_vector_type(4))) float floatx4;
typedef __attribute__((ext_vector_type(8))) short shortx8;
typedef unsigned short u16;

__device__ __forceinline__ u16 f2bf(float f) {
    union { float f; unsigned u; } v; v.f = f;
    unsigned r = v.u + 0x7fffu + ((v.u >> 16) & 1u);   // RNE
    return (u16)(r >> 16);
}

__device__ __forceinline__ shortx8 pack8(const float* v) {
    shortx8 r;
#pragma unroll
    for (int i = 0; i < 8; ++i) r[i] = (short)f2bf(v[i]);
    return r;
}

// async global->LDS, 16B per lane. LDS dest must be wave-uniform base + lane*16.
__device__ __forceinline__ void async_ld16(const void* g, void* l) {
    __builtin_amdgcn_global_load_lds(
        (const __attribute__((address_space(1))) unsigned int*)g,
        (__attribute__((address_space(3))) unsigned int*)l, 16, 0, 0);
}

// ---------------- routing: per-expert token lists ----------------
__global__ void route_kernel(const int* __restrict__ mask, const float* __restrict__ rw,
                             int* __restrict__ cnt, int* __restrict__ list,
                             float* __restrict__ wgt) {
    int t = blockIdx.x * blockDim.x + threadIdx.x;
    if (t >= NTOK) return;
#pragma unroll
    for (int e = 0; e < NEXP; ++e) {
#pragma unroll
        for (int k = 0; k < 2; ++k) {
            if (mask[(e * 2 + k) * NTOK + t] != 0) {
                int pos = atomicAdd(&cnt[e], 1);
                if (pos < CAP) {
                    list[e * CAP + pos] = t;
                    wgt[e * CAP + pos] = rw[t * 2 + k];
                }
            }
        }
    }
}

// ---------------- X: fp32 -> bf16, same layout ----------------
__global__ void xcvt_kernel(const float* __restrict__ X, u16* __restrict__ Xb) {
    const int i = (blockIdx.x * 256 + threadIdx.x) * 8;
    float4 a = *(const float4*)&X[i];
    float4 b = *(const float4*)&X[i + 4];
    float v[8] = {a.x, a.y, a.z, a.w, b.x, b.y, b.z, b.w};
    *(shortx8*)&Xb[i] = pack8(v);
}

// ---------------- W: [e][K][N] fp32 -> [e][N][K] bf16 (transpose+convert) ----------------
__global__ void transpose_cvt_kernel(const float* __restrict__ src, u16* __restrict__ dst,
                                     int K, int N) {
    const int e = blockIdx.z;
    src += (size_t)e * K * N;
    dst += (size_t)e * K * N;
    const int n0 = blockIdx.x * 64;
    const int k0 = blockIdx.y * 64;
    __shared__ u16 lds[64 * 72];
    const int t  = threadIdx.x;
    const int rr = t >> 4;      // 0..15
    const int c4 = t & 15;      // 0..15
#pragma unroll
    for (int it = 0; it < 4; ++it) {
        const int r = it * 16 + rr;
        float4 f = *(const float4*)&src[(size_t)(k0 + r) * N + n0 + c4 * 4];
        lds[(c4 * 4 + 0) * 72 + r] = f2bf(f.x);
        lds[(c4 * 4 + 1) * 72 + r] = f2bf(f.y);
        lds[(c4 * 4 + 2) * 72 + r] = f2bf(f.z);
        lds[(c4 * 4 + 3) * 72 + r] = f2bf(f.w);
    }
    __syncthreads();
    const int row8 = t >> 3;    // 0..31
    const int col8 = t & 7;     // 0..7
#pragma unroll
    for (int it = 0; it < 2; ++it) {
        const int row = it * 32 + row8;
        *(shortx8*)&dst[(size_t)(n0 + row) * K + k0 + col8 * 8] =
            *(const shortx8*)&lds[row * 72 + col8 * 8];
    }
}

// ---------------- GEMM1: H = silu(X w1) * (X w3) * rw, bf16 out ----------------
// A: gathered token rows of Xb [tok][HID]; B: W1b/W3b [e][INTER][HID] (n-major).
__global__ __launch_bounds__(256, 2)
void gemm1_kernel(const u16* __restrict__ Xb, const u16* __restrict__ W1b,
                  const u16* __restrict__ W3b, const int* __restrict__ cnt,
                  const int* __restrict__ list, const float* __restrict__ wgt,
                  u16* __restrict__ H) {
    const int e  = blockIdx.z;
    const int ce = min(cnt[e], CAP);
    const int m0 = blockIdx.y * BM;
    if (m0 >= ce) return;
    const int n0 = blockIdx.x * BN;

    __shared__ u16 lA [BM * BK];   // [row][k] 32 u16/row = 64B, no pad (global_load_lds)
    __shared__ u16 lB1[BN * BK];
    __shared__ u16 lB3[BN * BK];

    const int tid  = threadIdx.x;
    const int lane = tid & 63;
    const int wave = tid >> 6;

    // staging map: chunk c in {0,1}: lds u16-off = wave*1024 + c*512 + lane*8
    //   -> row = wave*32 + c*16 + lane/4, kcol = (lane&3)*8
    const int srow0 = wave * 32 + (lane >> 2);
    const int srow1 = srow0 + 16;
    const int scol  = (lane & 3) * 8;
    const int lo0 = wave * 1024 + lane * 8;
    const int lo1 = lo0 + 512;

    const int t0 = list[e * CAP + min(m0 + srow0, ce - 1)];
    const int t1 = list[e * CAP + min(m0 + srow1, ce - 1)];
    const u16* ap0  = Xb + (size_t)t0 * HID + scol;
    const u16* ap1  = Xb + (size_t)t1 * HID + scol;
    const u16* b1p0 = W1b + ((size_t)e * INTER + n0 + srow0) * HID + scol;
    const u16* b1p1 = b1p0 + (size_t)16 * HID;
    const u16* b3p0 = W3b + ((size_t)e * INTER + n0 + srow0) * HID + scol;
    const u16* b3p1 = b3p0 + (size_t)16 * HID;

    const int fl = lane & 15, fq = lane >> 4;
    const int wm  = (wave >> 1) * 64;
    const int wnn = (wave & 1) * 64;

    floatx4 acc1[4][4], acc3[4][4];
#pragma unroll
    for (int i = 0; i < 4; ++i)
#pragma unroll
        for (int j = 0; j < 4; ++j)
#pragma unroll
            for (int r = 0; r < 4; ++r) { acc1[i][j][r] = 0.f; acc3[i][j][r] = 0.f; }

    for (int k0 = 0; k0 < HID; k0 += BK) {
        __syncthreads();
        async_ld16(ap0  + k0, &lA [lo0]);
        async_ld16(ap1  + k0, &lA [lo1]);
        async_ld16(b1p0 + k0, &lB1[lo0]);
        async_ld16(b1p1 + k0, &lB1[lo1]);
        async_ld16(b3p0 + k0, &lB3[lo0]);
        async_ld16(b3p1 + k0, &lB3[lo1]);
        __syncthreads();

        shortx8 af[4], b1f[4], b3f[4];
#pragma unroll
        for (int i = 0; i < 4; ++i)
            af[i] = *(const shortx8*)&lA[(wm + i * 16 + fl) * BK + fq * 8];
#pragma unroll
        for (int j = 0; j < 4; ++j) {
            b1f[j] = *(const shortx8*)&lB1[(wnn + j * 16 + fl) * BK + fq * 8];
            b3f[j] = *(const shortx8*)&lB3[(wnn + j * 16 + fl) * BK + fq * 8];
        }
#pragma unroll
        for (int i = 0; i < 4; ++i)
#pragma unroll
            for (int j = 0; j < 4; ++j) {
                acc1[i][j] = __builtin_amdgcn_mfma_f32_16x16x32_bf16(af[i], b1f[j], acc1[i][j], 0, 0, 0);
                acc3[i][j] = __builtin_amdgcn_mfma_f32_16x16x32_bf16(af[i], b3f[j], acc3[i][j], 0, 0, 0);
            }
    }

    // epilogue: silu(a1)*a3 * rw -> bf16 H
#pragma unroll
    for (int i = 0; i < 4; ++i) {
        const int rowb = m0 + wm + i * 16 + fq * 4;
#pragma unroll
        for (int r = 0; r < 4; ++r) {
            const int row = rowb + r;
            const bool valid = row < ce;
            const float rwv = valid ? wgt[e * CAP + row] : 0.f;
            u16* hp = H + (size_t)(e * CAP + (valid ? row : 0)) * INTER;
#pragma unroll
            for (int j = 0; j < 4; ++j) {
                const int col = n0 + wnn + j * 16 + fl;
                float h1 = acc1[i][j][r];
                float h3 = acc3[i][j][r];
                float sv = h1 / (1.f + __expf(-h1)) * h3 * rwv;
                if (valid) hp[col] = f2bf(sv);
            }
        }
    }
}

// ---------------- GEMM2: out[tok] += H w2 ----------------
// A: H rows [e*CAP+row][INTER] bf16; B: W2b [e][HID][INTER] (n-major).
__global__ __launch_bounds__(256, 2)
void gemm2_kernel(const u16* __restrict__ H, const u16* __restrict__ W2b,
                  const int* __restrict__ cnt, const int* __restrict__ list,
                  float* __restrict__ out) {
    const int e  = blockIdx.z;
    const int ce = min(cnt[e], CAP);
    const int m0 = blockIdx.y * BM;
    if (m0 >= ce) return;
    const int n0 = blockIdx.x * BN;

    __shared__ u16 lA[BM * BK];
    __shared__ u16 lB[BN * BK];

    const int tid  = threadIdx.x;
    const int lane = tid & 63;
    const int wave = tid >> 6;

    const int srow0 = wave * 32 + (lane >> 2);
    const int srow1 = srow0 + 16;
    const int scol  = (lane & 3) * 8;
    const int lo0 = wave * 1024 + lane * 8;
    const int lo1 = lo0 + 512;

    const u16* ap0 = H + (size_t)(e * CAP + m0 + srow0) * INTER + scol;  // rows >= ce: poison, masked later
    const u16* ap1 = ap0 + (size_t)16 * INTER;
    const u16* bp0 = W2b + ((size_t)e * HID + n0 + srow0) * INTER + scol;
    const u16* bp1 = bp0 + (size_t)16 * INTER;

    const int fl = lane & 15, fq = lane >> 4;
    const int wm  = (wave >> 1) * 64;
    const int wnn = (wave & 1) * 64;

    floatx4 acc[4][4];
#pragma unroll
    for (int i = 0; i < 4; ++i)
#pragma unroll
        for (int j = 0; j < 4; ++j)
#pragma unroll
            for (int r = 0; r < 4; ++r) acc[i][j][r] = 0.f;

    for (int k0 = 0; k0 < INTER; k0 += BK) {
        __syncthreads();
        async_ld16(ap0 + k0, &lA[lo0]);
        async_ld16(ap1 + k0, &lA[lo1]);
        async_ld16(bp0 + k0, &lB[lo0]);
        async_ld16(bp1 + k0, &lB[lo1]);
        __syncthreads();

        shortx8 af[4], bf[4];
#pragma unroll
        for (int i = 0; i < 4; ++i)
            af[i] = *(const shortx8*)&lA[(wm + i * 16 + fl) * BK + fq * 8];
#pragma unroll
        for (int j = 0; j < 4; ++j)
            bf[j] = *(const shortx8*)&lB[(wnn + j * 16 + fl) * BK + fq * 8];
#pragma unroll
        for (int i = 0; i < 4; ++i)
#pragma unroll
            for (int j = 0; j < 4; ++j)
                acc[i][j] = __builtin_amdgcn_mfma_f32_16x16x32_bf16(af[i], bf[j], acc[i][j], 0, 0, 0);
    }

#pragma unroll
    for (int i = 0; i < 4; ++i) {
        const int rowb = m0 + wm + i * 16 + fq * 4;
#pragma unroll
        for (int r = 0; r < 4; ++r) {
            const int row = rowb + r;
            const bool valid = row < ce;
            const int tok = valid ? list[e * CAP + row] : 0;
            float* op = out + (size_t)tok * HID;
#pragma unroll
            for (int j = 0; j < 4; ++j) {
                const int col = n0 + wnn + j * 16 + fl;
                if (valid) atomicAdd(&op[col], acc[i][j][r]);
            }
        }
    }
}

extern "C" void kernel_launch(void* const* d_in, const int* in_sizes, int n_in,
                              void* d_out, int out_size, void* d_ws, size_t ws_size,
                              hipStream_t stream) {
    const int*   mask = (const int*)  d_in[0];
    const float* X    = (const float*)d_in[1];
    const float* rw   = (const float*)d_in[2];
    const float* w1   = (const float*)d_in[3];
    const float* w2   = (const float*)d_in[4];
    const float* w3   = (const float*)d_in[5];
    float* out = (float*)d_out;

    char* ws = (char*)d_ws;
    size_t off = 0;
    int*   cnt  = (int*)(ws + off);  off += 256;
    int*   list = (int*)(ws + off);  off += (size_t)NEXP * CAP * 4;      // 64 KB
    float* wgt  = (float*)(ws + off); off += (size_t)NEXP * CAP * 4;     // 64 KB
    u16*   Xb   = (u16*)(ws + off);  off += (size_t)NTOK * HID * 2;      // 8 MB
    u16*   W1b  = (u16*)(ws + off);  off += (size_t)NEXP * HID * INTER * 2;  // 56 MB
    u16*   W3b  = (u16*)(ws + off);  off += (size_t)NEXP * HID * INTER * 2;  // 56 MB
    u16*   W2b  = (u16*)(ws + off);  off += (size_t)NEXP * HID * INTER * 2;  // 56 MB
    u16*   H    = (u16*)(ws + off);  off += (size_t)NEXP * CAP * INTER * 2;  // 112 MB

    hipMemsetAsync(cnt, 0, 256, stream);
    hipMemsetAsync(d_out, 0, (size_t)out_size * sizeof(float), stream);

    route_kernel<<<dim3((NTOK + 255) / 256), dim3(256), 0, stream>>>(mask, rw, cnt, list, wgt);
    xcvt_kernel<<<dim3(NTOK * HID / (256 * 8)), dim3(256), 0, stream>>>(X, Xb);
    // w1/w3: [e][HID][INTER] -> [e][INTER][HID]
    transpose_cvt_kernel<<<dim3(INTER / 64, HID / 64, NEXP), dim3(256), 0, stream>>>(w1, W1b, HID, INTER);
    transpose_cvt_kernel<<<dim3(INTER / 64, HID / 64, NEXP), dim3(256), 0, stream>>>(w3, W3b, HID, INTER);
    // w2: [e][INTER][HID] -> [e][HID][INTER]
    transpose_cvt_kernel<<<dim3(HID / 64, INTER / 64, NEXP), dim3(256), 0, stream>>>(w2, W2b, INTER, HID);

    gemm1_kernel<<<dim3(INTER / BN, CAP / BM, NEXP), dim3(256), 0, stream>>>(Xb, W1b, W3b, cnt, list, wgt, H);
    gemm2_kernel<<<dim3(HID / BN, CAP / BM, NEXP), dim3(256), 0, stream>>>(H, W2b, cnt, list, out);
}